// Round 5
// baseline (124.674 us; speedup 1.0000x reference)
//
#include <hip/hip_runtime.h>
#include <math.h>
#include <float.h>

#define BN 2
#define NP 1024
#define NC 81
#define ND 100
#define MAXC 8192
#define CAP2 512      // per-class candidate cap (M ~ 30, binomial tail; 512 is >>80 sigma)
#define CAPT 512      // tail compacted-superset cap
#define NBIN 4096
#define SCORE_T 0.05f
#define NMS_T 0.5f
#define BBOX_CLIP 4.135166556742356f   // log(1000/16)

typedef unsigned long long ull;

// Decode one box, identical op order everywhere so results are bit-equal across uses.
__device__ __forceinline__ void decode_box(
    const float* __restrict__ props, const float* __restrict__ regress,
    int b, int n, int c, float& x1, float& y1, float& x2, float& y2)
{
    const float* pr = props + ((size_t)b * NP + n) * 4;
    float p0 = pr[0], p1 = pr[1], p2 = pr[2], p3 = pr[3];
    float w  = p2 - p0 + 1.0f, h = p3 - p1 + 1.0f;
    float cx = p0 + 0.5f * w,  cy = p1 + 0.5f * h;
    const float* rl = regress + (((size_t)b * NP + n) * NC + c) * 4;
    float dx = rl[0] / 10.0f, dy = rl[1] / 10.0f;
    float dw = fminf(rl[2] / 5.0f, BBOX_CLIP);
    float dh = fminf(rl[3] / 5.0f, BBOX_CLIP);
    float pcx = dx * w + cx, pcy = dy * h + cy;
    float pw  = expf(dw) * w, ph = expf(dh) * h;
    x1 = pcx - 0.5f * pw; y1 = pcy - 0.5f * ph;
    x2 = pcx + 0.5f * pw - 1.0f; y2 = pcy + 0.5f * ph - 1.0f;
    x1 = fminf(fmaxf(x1, 0.f), 1023.f);
    y1 = fminf(fmaxf(y1, 0.f), 1023.f);
    x2 = fminf(fmaxf(x2, 0.f), 1023.f);
    y2 = fminf(fmaxf(y2, 0.f), 1023.f);
}

__device__ __forceinline__ void emit_slot(
    float* __restrict__ out, const float* __restrict__ props,
    const float* __restrict__ regress, int b, int d, ull key)
{
    float score = __uint_as_float((unsigned int)(key >> 32));
    float* ob = out + ((size_t)b * ND + d) * 4;
    float* os = out + (size_t)BN * ND * 4 + b * ND + d;
    float* ol = out + (size_t)BN * ND * 5 + b * ND + d;
    if (score > 0.f) {
        unsigned int f = 0xFFFFFFFFu - (unsigned int)(key & 0xFFFFFFFFu);
        int cls = f / NP, n = f % NP;
        float x1, y1, x2, y2;
        decode_box(props, regress, b, n, cls + 1, x1, y1, x2, y2);
        ob[0] = x1; ob[1] = y1; ob[2] = x2; ob[3] = y2;
        *os = score;
        *ol = (float)(cls + 1);
    } else {
        ob[0] = 0.f; ob[1] = 0.f; ob[2] = 0.f; ob[3] = 0.f;
        *os = 0.f;
        *ol = -1.f;
    }
}

__device__ __forceinline__ void bitonic_desc(ull* a, int len, int tid, int nthr)
{
    for (int k = 2; k <= len; k <<= 1) {
        for (int j = k >> 1; j > 0; j >>= 1) {
            for (int i = tid; i < len; i += nthr) {
                int ixj = i ^ j;
                if (ixj > i) {
                    bool desc = ((i & k) == 0);
                    ull x = a[i], y = a[ixj];
                    if (desc ? (x < y) : (x > y)) { a[i] = y; a[ixj] = x; }
                }
            }
            __syncthreads();
        }
    }
}

// ---------------- Kernel A: softmax -> transposed per-class probs + init counters -------
// probs_t[b][cls][n]; bit-identical to rounds 2-4 (sequential max/sum per row).
// Thread 0 zeroes cnt/done; kernel completion is a release so kernel B sees them.
__global__ __launch_bounds__(64) void softmax_probs_kernel(
    const float* __restrict__ logits, float* __restrict__ probs_t,
    int* __restrict__ cnt, int* __restrict__ done)
{
    int g = blockIdx.x * 64 + threadIdx.x;
    if (g == 0) { cnt[0] = 0; cnt[1] = 0; done[0] = 0; done[1] = 0; }
    if (g >= BN * NP) return;
    int b = g / NP, n = g % NP;
    const float* row = logits + (size_t)g * NC;
    float r[NC];
    #pragma unroll
    for (int i = 0; i < NC; ++i) r[i] = row[i];
    float m = -FLT_MAX;
    #pragma unroll
    for (int i = 0; i < NC; ++i) m = fmaxf(m, r[i]);
    float e[NC];
    float s = 0.f;
    #pragma unroll
    for (int i = 0; i < NC; ++i) { e[i] = expf(r[i] - m); s += e[i]; }
    #pragma unroll
    for (int c = 1; c < NC; ++c)
        probs_t[((size_t)b * (NC - 1) + (c - 1)) * NP + n] = e[c] / s;
}

// ---------------- Kernel B: per-(image,class) NMS + tail-block top-100 ----------------
__global__ __launch_bounds__(64) void nms_topk_kernel(
    const float* __restrict__ probs_t, const float* __restrict__ regress,
    const float* __restrict__ props, int* __restrict__ cnt, int* __restrict__ done,
    ull* __restrict__ g_key, float* __restrict__ out)
{
    const int tid = threadIdx.x;
    const int idx = blockIdx.x;
    const int b   = idx / (NC - 1);
    const int cls = idx % (NC - 1);
    const int c   = cls + 1;

    __shared__ union {
        struct {                                  // NMS phase: 16 KB
            ull   key[CAP2];
            float x1[CAP2], y1[CAP2], x2[CAP2], y2[CAP2], area[CAP2];
            int   keep[CAP2];
        } a;
        struct {                                  // tail phase: 20 KB
            int hist[NBIN];
            ull cbuf[CAPT];
        } t;
    } sm;
    __shared__ int s_cnt, s_ret, s_bstar, s_cnt2;

    if (tid == 0) s_cnt = 0;
    __syncthreads();

    // --- scan this class's prob row (coalesced), compact candidates as packed keys ---
    const float* prow = probs_t + ((size_t)b * (NC - 1) + cls) * NP;
    for (int n = tid; n < NP; n += 64) {
        float p = prow[n];
        if (p > SCORE_T) {
            int k = atomicAdd(&s_cnt, 1);
            if (k < CAP2)
                sm.a.key[k] = ((ull)__float_as_uint(p) << 32)
                            | (ull)(0xFFFFFFFFu - (unsigned)n);
        }
    }
    __syncthreads();
    int M = s_cnt; if (M > CAP2) M = CAP2;

    if (M > 0) {
        int Mp = 2; while (Mp < M) Mp <<= 1;
        for (int i = M + tid; i < Mp; i += 64) sm.a.key[i] = 0ull;
        __syncthreads();

        bitonic_desc(sm.a.key, Mp, tid, 64);      // desc score, asc n on ties

        // --- decode the M live candidates ---
        for (int i = tid; i < M; i += 64) {
            int n = (int)(0xFFFFFFFFu - (unsigned)(sm.a.key[i] & 0xFFFFFFFFu));
            float x1, y1, x2, y2;
            decode_box(props, regress, b, n, c, x1, y1, x2, y2);
            sm.a.x1[i] = x1; sm.a.y1[i] = y1; sm.a.x2[i] = x2; sm.a.y2[i] = y2;
            sm.a.area[i] = (x2 - x1 + 1.f) * (y2 - y1 + 1.f);
            sm.a.keep[i] = 1;
        }
        __syncthreads();

        // --- greedy NMS: i sequential, suppression parallel ---
        for (int i = 0; i < M; ++i) {
            if (sm.a.keep[i]) {
                float x1i = sm.a.x1[i], y1i = sm.a.y1[i];
                float x2i = sm.a.x2[i], y2i = sm.a.y2[i], ai = sm.a.area[i];
                for (int j = i + 1 + tid; j < M; j += 64) {
                    float lx = fmaxf(x1i, sm.a.x1[j]);
                    float ly = fmaxf(y1i, sm.a.y1[j]);
                    float rx = fminf(x2i, sm.a.x2[j]);
                    float ry = fminf(y2i, sm.a.y2[j]);
                    float wd = fmaxf(rx - lx + 1.f, 0.f);
                    float ht = fmaxf(ry - ly + 1.f, 0.f);
                    float inter = wd * ht;
                    float iou = inter / (ai + sm.a.area[j] - inter);
                    if (iou > NMS_T) sm.a.keep[j] = 0;
                }
            }
            __syncthreads();
        }

        // --- append survivors: key -> (score | ~flat) ---
        for (int i = tid; i < M; i += 64) {
            if (sm.a.keep[i]) {
                int pos = atomicAdd(&cnt[b], 1);
                if (pos < MAXC) {
                    ull key = sm.a.key[i];
                    unsigned n = 0xFFFFFFFFu - (unsigned)(key & 0xFFFFFFFFu);
                    unsigned f = (unsigned)cls * NP + n;
                    g_key[(size_t)b * MAXC + pos] =
                        (key & 0xFFFFFFFF00000000ull) | (ull)(0xFFFFFFFFu - f);
                }
            }
        }
    }

    // --- done-counter; last block of this image runs top-K inline ---
    __threadfence();
    if (tid == 0) s_ret = atomicAdd(&done[b], 1);
    __syncthreads();
    if (s_ret != (NC - 1) - 1) return;
    __threadfence();

    int K = atomicAdd(&cnt[b], 0); if (K > MAXC) K = MAXC;
    ull* keys = g_key + (size_t)b * MAXC;

    for (int i = tid; i < NBIN; i += 64) sm.t.hist[i] = 0;
    if (tid == 0) s_cnt2 = 0;
    __syncthreads();

    for (int i = tid; i < K; i += 64)
        atomicAdd(&sm.t.hist[(int)(keys[i] >> 52)], 1);
    __syncthreads();

    // boundary bin b*: one wave, suffix scan over 4096 bins (64 groups x 64)
    {
        int l = tid;
        int gs = 0;
        for (int q = 0; q < 64; ++q) gs += sm.t.hist[l * 64 + q];
        int pre = gs;
        for (int off = 1; off < 64; off <<= 1) {
            int v = __shfl_up(pre, off, 64);
            if (l >= off) pre += v;
        }
        int total = __shfl(pre, 63, 64);
        int S = total - pre + gs;                        // keys in groups >= l
        ull ball = __ballot(S >= ND);
        int gstar = ball ? (63 - __clzll((long long)ball)) : 0;
        int Sg = __shfl(S, gstar, 64);
        int Gg = __shfl(gs, gstar, 64);
        int A  = Sg - Gg;                                // keys in groups > gstar
        int h  = sm.t.hist[gstar * 64 + l];
        int pre2 = h;
        for (int off = 1; off < 64; off <<= 1) {
            int v = __shfl_up(pre2, off, 64);
            if (l >= off) pre2 += v;
        }
        int T = Gg - pre2 + h;                           // suffix within group
        ull ball2 = __ballot(A + T >= ND);
        int binin = ball2 ? (63 - __clzll((long long)ball2)) : 0;
        if (l == 0) s_bstar = gstar * 64 + binin;
    }
    __syncthreads();
    const int bstar = s_bstar;

    // compact superset (every excluded key is numerically smaller)
    for (int i = tid; i < K; i += 64) {
        ull key = keys[i];
        if ((int)(key >> 52) >= bstar) {
            int p = atomicAdd(&s_cnt2, 1);
            if (p < CAPT) sm.t.cbuf[p] = key;
        }
    }
    __syncthreads();
    const int Tt = s_cnt2;

    if (Tt <= CAPT) {
        int Tp = 128; while (Tp < Tt) Tp <<= 1;
        for (int i = Tt + tid; i < Tp; i += 64) sm.t.cbuf[i] = 0ull;
        __syncthreads();
        bitonic_desc(sm.t.cbuf, Tp, tid, 64);
        for (int d = tid; d < ND; d += 64)
            emit_slot(out, props, regress, b, d, sm.t.cbuf[d]);
    } else {
        // fallback (statistically unreachable): ND destructive argmax rounds, wave-reduced
        for (int d = 0; d < ND; ++d) {
            ull bk = 0ull; int bp = -1;
            for (int t = tid; t < K; t += 64) {
                ull k2 = keys[t];
                if (k2 > bk) { bk = k2; bp = t; }
            }
            for (int off = 32; off > 0; off >>= 1) {
                ull ok = __shfl_down(bk, off, 64);
                int op = __shfl_down(bp, off, 64);
                if (ok > bk) { bk = ok; bp = op; }
            }
            bk = __shfl(bk, 0, 64); bp = __shfl(bp, 0, 64);
            if (tid == 0) {
                emit_slot(out, props, regress, b, d, bk);
                if (bp >= 0) keys[bp] = 0ull;
            }
            __threadfence();
            __syncthreads();
        }
    }
}

extern "C" void kernel_launch(void* const* d_in, const int* in_sizes, int n_in,
                              void* d_out, int out_size, void* d_ws, size_t ws_size,
                              hipStream_t stream) {
    const float* logits  = (const float*)d_in[0];   // [B, N, C]
    const float* regress = (const float*)d_in[1];   // [B, N, C*4]
    const float* props   = (const float*)d_in[2];   // [B, N, 4]
    float* out = (float*)d_out;                     // boxes(800) | scores(200) | labels(200)

    // Workspace layout (no overlap):
    //   [0      , 8     )  cnt     : 2 ints   (zeroed by kernel A)
    //   [8      , 16    )  done    : 2 ints   (zeroed by kernel A)
    //   [256    , 655616)  probs_t : BN*(NC-1)*NP floats (640 KB)
    //   [655616 , 786688)  g_key   : BN*MAXC u64 (128 KB)
    char* ws = (char*)d_ws;
    int*   cnt     = (int*)  (ws);
    int*   done    = (int*)  (ws + 8);
    float* probs_t = (float*)(ws + 256);
    ull*   g_key   = (ull*)  (ws + 256 + (size_t)BN * (NC - 1) * NP * 4);

    hipLaunchKernelGGL(softmax_probs_kernel, dim3(BN * NP / 64), dim3(64), 0, stream,
                       logits, probs_t, cnt, done);
    hipLaunchKernelGGL(nms_topk_kernel, dim3(BN * (NC - 1)), dim3(64), 0, stream,
                       probs_t, regress, props, cnt, done, g_key, out);
}

// Round 6
// 111.115 us; speedup vs baseline: 1.1220x; 1.1220x over previous
//
#include <hip/hip_runtime.h>
#include <math.h>
#include <float.h>

#define BN 2
#define NP 1024
#define NC 81
#define ND 100
#define MAXC 8192
#define CAP2 512      // general-path candidate cap (M~30; >64 triggers general path)
#define CAPT 512      // tail compacted-superset cap
#define NBIN 4096
#define SCORE_T 0.05f
#define NMS_T 0.5f
#define BBOX_CLIP 4.135166556742356f   // log(1000/16)

typedef unsigned long long ull;

// Decode one box, identical op order everywhere so results are bit-equal across uses.
__device__ __forceinline__ void decode_box(
    const float* __restrict__ props, const float* __restrict__ regress,
    int b, int n, int c, float& x1, float& y1, float& x2, float& y2)
{
    const float* pr = props + ((size_t)b * NP + n) * 4;
    float p0 = pr[0], p1 = pr[1], p2 = pr[2], p3 = pr[3];
    float w  = p2 - p0 + 1.0f, h = p3 - p1 + 1.0f;
    float cx = p0 + 0.5f * w,  cy = p1 + 0.5f * h;
    const float* rl = regress + (((size_t)b * NP + n) * NC + c) * 4;
    float dx = rl[0] / 10.0f, dy = rl[1] / 10.0f;
    float dw = fminf(rl[2] / 5.0f, BBOX_CLIP);
    float dh = fminf(rl[3] / 5.0f, BBOX_CLIP);
    float pcx = dx * w + cx, pcy = dy * h + cy;
    float pw  = expf(dw) * w, ph = expf(dh) * h;
    x1 = pcx - 0.5f * pw; y1 = pcy - 0.5f * ph;
    x2 = pcx + 0.5f * pw - 1.0f; y2 = pcy + 0.5f * ph - 1.0f;
    x1 = fminf(fmaxf(x1, 0.f), 1023.f);
    y1 = fminf(fmaxf(y1, 0.f), 1023.f);
    x2 = fminf(fmaxf(x2, 0.f), 1023.f);
    y2 = fminf(fmaxf(y2, 0.f), 1023.f);
}

__device__ __forceinline__ void emit_slot(
    float* __restrict__ out, const float* __restrict__ props,
    const float* __restrict__ regress, int b, int d, ull key)
{
    float score = __uint_as_float((unsigned int)(key >> 32));
    float* ob = out + ((size_t)b * ND + d) * 4;
    float* os = out + (size_t)BN * ND * 4 + b * ND + d;
    float* ol = out + (size_t)BN * ND * 5 + b * ND + d;
    if (score > 0.f) {
        unsigned int f = 0xFFFFFFFFu - (unsigned int)(key & 0xFFFFFFFFu);
        int cls = f / NP, n = f % NP;
        float x1, y1, x2, y2;
        decode_box(props, regress, b, n, cls + 1, x1, y1, x2, y2);
        ob[0] = x1; ob[1] = y1; ob[2] = x2; ob[3] = y2;
        *os = score;
        *ol = (float)(cls + 1);
    } else {
        ob[0] = 0.f; ob[1] = 0.f; ob[2] = 0.f; ob[3] = 0.f;
        *os = 0.f;
        *ol = -1.f;
    }
}

__device__ __forceinline__ void bitonic_desc(ull* a, int len, int tid, int nthr)
{
    for (int k = 2; k <= len; k <<= 1) {
        for (int j = k >> 1; j > 0; j >>= 1) {
            for (int i = tid; i < len; i += nthr) {
                int ixj = i ^ j;
                if (ixj > i) {
                    bool desc = ((i & k) == 0);
                    ull x = a[i], y = a[ixj];
                    if (desc ? (x < y) : (x > y)) { a[i] = y; a[ixj] = x; }
                }
            }
            __syncthreads();
        }
    }
}

// ---------------- Kernel A: softmax -> transposed per-class probs + init counters -------
__global__ __launch_bounds__(256) void softmax_probs_kernel(
    const float* __restrict__ logits, float* __restrict__ probs_t,
    int* __restrict__ cnt, int* __restrict__ done)
{
    int g = blockIdx.x * 256 + threadIdx.x;
    if (g == 0) { cnt[0] = 0; cnt[1] = 0; done[0] = 0; done[1] = 0; }
    if (g >= BN * NP) return;
    int b = g / NP, n = g % NP;
    const float* row = logits + (size_t)g * NC;
    float m = -FLT_MAX;
    for (int i = 0; i < NC; ++i) m = fmaxf(m, row[i]);
    float s = 0.f;
    for (int i = 0; i < NC; ++i) s += expf(row[i] - m);
    for (int c = 1; c < NC; ++c)
        probs_t[((size_t)b * (NC - 1) + (c - 1)) * NP + n] = expf(row[c] - m) / s;
}

// ---------------- Kernel B: per-(image,class) NMS (register fast path) + tail top-100 ---
__global__ __launch_bounds__(256) void nms_topk_kernel(
    const float* __restrict__ probs_t, const float* __restrict__ regress,
    const float* __restrict__ props, int* __restrict__ cnt, int* __restrict__ done,
    ull* __restrict__ g_key, float* __restrict__ out)
{
    const int tid  = threadIdx.x;
    const int wave = tid >> 6;
    const int l    = tid & 63;
    const int idx  = blockIdx.x;
    const int b    = idx / (NC - 1);
    const int cls  = idx % (NC - 1);
    const int c    = cls + 1;

    __shared__ union {
        struct {                                  // general NMS path: 16 KB
            ull   key[CAP2];
            float x1[CAP2], y1[CAP2], x2[CAP2], y2[CAP2], area[CAP2];
            int   keep[CAP2];
        } a;
        struct {                                  // tail phase: 20 KB
            int hist[NBIN];
            ull cbuf[CAPT];
        } t;
    } sm;
    __shared__ int s_cnt, s_ret, s_bstar, s_cnt2;

    if (tid == 0) s_cnt = 0;
    __syncthreads();

    // --- scan: one float4 per thread covers the whole 1024-prob row ---
    const float* prow = probs_t + ((size_t)b * (NC - 1) + cls) * NP;
    float4 v = ((const float4*)prow)[tid];
    #pragma unroll
    for (int q = 0; q < 4; ++q) {
        float p = (&v.x)[q];
        if (p > SCORE_T) {
            int k = atomicAdd(&s_cnt, 1);
            if (k < CAP2) {
                unsigned n = (unsigned)(tid * 4 + q);
                sm.a.key[k] = ((ull)__float_as_uint(p) << 32)
                            | (ull)(0xFFFFFFFFu - n);
            }
        }
    }
    __syncthreads();
    int M = s_cnt; if (M > CAP2) M = CAP2;

    if (M > 64) {
        // ---------- general path (rare): LDS bitonic + barriered NMS, 256 threads -----
        int Mp = 128; while (Mp < M) Mp <<= 1;
        for (int i = M + tid; i < Mp; i += 256) sm.a.key[i] = 0ull;
        __syncthreads();
        bitonic_desc(sm.a.key, Mp, tid, 256);
        for (int i = tid; i < M; i += 256) {
            int n = (int)(0xFFFFFFFFu - (unsigned)(sm.a.key[i] & 0xFFFFFFFFu));
            float x1, y1, x2, y2;
            decode_box(props, regress, b, n, c, x1, y1, x2, y2);
            sm.a.x1[i] = x1; sm.a.y1[i] = y1; sm.a.x2[i] = x2; sm.a.y2[i] = y2;
            sm.a.area[i] = (x2 - x1 + 1.f) * (y2 - y1 + 1.f);
            sm.a.keep[i] = 1;
        }
        __syncthreads();
        for (int i = 0; i < M; ++i) {
            if (sm.a.keep[i]) {
                float x1i = sm.a.x1[i], y1i = sm.a.y1[i];
                float x2i = sm.a.x2[i], y2i = sm.a.y2[i], ai = sm.a.area[i];
                for (int j = i + 1 + tid; j < M; j += 256) {
                    float lx = fmaxf(x1i, sm.a.x1[j]);
                    float ly = fmaxf(y1i, sm.a.y1[j]);
                    float rx = fminf(x2i, sm.a.x2[j]);
                    float ry = fminf(y2i, sm.a.y2[j]);
                    float wd = fmaxf(rx - lx + 1.f, 0.f);
                    float ht = fmaxf(ry - ly + 1.f, 0.f);
                    float inter = wd * ht;
                    float iou = inter / (ai + sm.a.area[j] - inter);
                    if (iou > NMS_T) sm.a.keep[j] = 0;
                }
            }
            __syncthreads();
        }
        for (int i = tid; i < M; i += 256) {
            if (sm.a.keep[i]) {
                int pos = atomicAdd(&cnt[b], 1);
                if (pos < MAXC) {
                    ull key = sm.a.key[i];
                    unsigned n = 0xFFFFFFFFu - (unsigned)(key & 0xFFFFFFFFu);
                    unsigned f = (unsigned)cls * NP + n;
                    g_key[(size_t)b * MAXC + pos] =
                        (key & 0xFFFFFFFF00000000ull) | (ull)(0xFFFFFFFFu - f);
                }
            }
        }
    } else if (M > 0) {
        // ---------- fast path: whole NMS in wave-0 registers, no LDS, no barriers -----
        if (wave == 0) {
            ull key = (l < M) ? sm.a.key[l] : 0ull;
            // in-register bitonic sort, descending (score desc, n asc on ties)
            #pragma unroll
            for (int k = 2; k <= 64; k <<= 1) {
                #pragma unroll
                for (int j = k >> 1; j > 0; j >>= 1) {
                    ull p = __shfl_xor(key, j, 64);
                    bool lower = (l & j) == 0;
                    bool up    = (l & k) != 0;        // flipped -> descending network
                    ull mn = key < p ? key : p;
                    ull mx = key < p ? p : key;
                    key = (lower == up) ? mn : mx;
                }
            }
            float x1 = 0.f, y1 = 0.f, x2 = 0.f, y2 = 0.f, ar = 0.f;
            if (l < M) {
                int n = (int)(0xFFFFFFFFu - (unsigned)(key & 0xFFFFFFFFu));
                decode_box(props, regress, b, n, c, x1, y1, x2, y2);
                ar = (x2 - x1 + 1.f) * (y2 - y1 + 1.f);
            }
            // greedy NMS: wave-uniform keep mask; suppressed i skipped uniformly
            ull keep = (M >= 64) ? ~0ull : ((1ull << M) - 1ull);
            for (int i = 0; i < M; ++i) {
                if ((keep >> i) & 1ull) {
                    float xi1 = __shfl(x1, i, 64), yi1 = __shfl(y1, i, 64);
                    float xi2 = __shfl(x2, i, 64), yi2 = __shfl(y2, i, 64);
                    float ari = __shfl(ar, i, 64);
                    float lx = fmaxf(xi1, x1), ly = fmaxf(yi1, y1);
                    float rx = fminf(xi2, x2), ry = fminf(yi2, y2);
                    float wd = fmaxf(rx - lx + 1.f, 0.f);
                    float ht = fmaxf(ry - ly + 1.f, 0.f);
                    float inter = wd * ht;
                    float iou = inter / (ari + ar - inter);
                    ull sup = __ballot(iou > NMS_T && l > i);
                    keep &= ~sup;     // bits >= M were never set; extra sup bits harmless
                }
            }
            int nk = __popcll(keep);
            int basep = 0;
            if (l == 0 && nk > 0) basep = atomicAdd(&cnt[b], nk);
            basep = __shfl(basep, 0, 64);
            if ((keep >> l) & 1ull) {
                int pos = basep + __popcll(keep & ((1ull << l) - 1ull));
                if (pos < MAXC) {
                    unsigned n = 0xFFFFFFFFu - (unsigned)(key & 0xFFFFFFFFu);
                    unsigned f = (unsigned)cls * NP + n;
                    g_key[(size_t)b * MAXC + pos] =
                        (key & 0xFFFFFFFF00000000ull) | (ull)(0xFFFFFFFFu - f);
                }
            }
        }
    }

    // --- done-counter; last block of this image runs top-K inline ---
    __syncthreads();
    __threadfence();
    if (tid == 0) s_ret = atomicAdd(&done[b], 1);
    __syncthreads();
    if (s_ret != (NC - 1) - 1) return;
    __threadfence();

    int K = atomicAdd(&cnt[b], 0); if (K > MAXC) K = MAXC;
    ull* keys = g_key + (size_t)b * MAXC;

    for (int i = tid; i < NBIN; i += 256) sm.t.hist[i] = 0;
    if (tid == 0) s_cnt2 = 0;
    __syncthreads();

    for (int i = tid; i < K; i += 256)
        atomicAdd(&sm.t.hist[(int)(keys[i] >> 52)], 1);
    __syncthreads();

    // boundary bin b*: wave 0, suffix scan over 4096 bins (64 groups x 64)
    if (tid < 64) {
        int gs = 0;
        for (int q = 0; q < 64; ++q) gs += sm.t.hist[l * 64 + q];
        int pre = gs;
        for (int off = 1; off < 64; off <<= 1) {
            int vv = __shfl_up(pre, off, 64);
            if (l >= off) pre += vv;
        }
        int total = __shfl(pre, 63, 64);
        int S = total - pre + gs;                        // keys in groups >= l
        ull ball = __ballot(S >= ND);
        int gstar = ball ? (63 - __clzll((long long)ball)) : 0;
        int Sg = __shfl(S, gstar, 64);
        int Gg = __shfl(gs, gstar, 64);
        int A  = Sg - Gg;                                // keys in groups > gstar
        int h  = sm.t.hist[gstar * 64 + l];
        int pre2 = h;
        for (int off = 1; off < 64; off <<= 1) {
            int vv = __shfl_up(pre2, off, 64);
            if (l >= off) pre2 += vv;
        }
        int T = Gg - pre2 + h;                           // suffix within group
        ull ball2 = __ballot(A + T >= ND);
        int binin = ball2 ? (63 - __clzll((long long)ball2)) : 0;
        if (l == 0) s_bstar = gstar * 64 + binin;
    }
    __syncthreads();
    const int bstar = s_bstar;

    // compact superset (every excluded key is numerically smaller)
    for (int i = tid; i < K; i += 256) {
        ull key = keys[i];
        if ((int)(key >> 52) >= bstar) {
            int p = atomicAdd(&s_cnt2, 1);
            if (p < CAPT) sm.t.cbuf[p] = key;
        }
    }
    __syncthreads();
    const int Tt = s_cnt2;

    if (Tt <= CAPT) {
        int Tp = 128; while (Tp < Tt) Tp <<= 1;
        for (int i = Tt + tid; i < Tp; i += 256) sm.t.cbuf[i] = 0ull;
        __syncthreads();
        bitonic_desc(sm.t.cbuf, Tp, tid, 256);
        for (int d = tid; d < ND; d += 256)
            emit_slot(out, props, regress, b, d, sm.t.cbuf[d]);
    } else {
        // fallback (statistically unreachable): ND destructive argmax rounds
        ull* rk = sm.a.key;            // reuse union (tail sm.t dead in this branch)
        int* rp = sm.a.keep;
        for (int d = 0; d < ND; ++d) {
            ull bk = 0ull; int bp = -1;
            for (int t = tid; t < K; t += 256) {
                ull k2 = keys[t];
                if (k2 > bk) { bk = k2; bp = t; }
            }
            rk[tid] = bk; rp[tid] = bp;
            __syncthreads();
            for (int off = 128; off > 0; off >>= 1) {
                if (tid < off && rk[tid + off] > rk[tid]) {
                    rk[tid] = rk[tid + off]; rp[tid] = rp[tid + off];
                }
                __syncthreads();
            }
            if (tid == 0) {
                emit_slot(out, props, regress, b, d, rk[0]);
                if (rp[0] >= 0) keys[rp[0]] = 0ull;
            }
            __syncthreads();
        }
    }
}

extern "C" void kernel_launch(void* const* d_in, const int* in_sizes, int n_in,
                              void* d_out, int out_size, void* d_ws, size_t ws_size,
                              hipStream_t stream) {
    const float* logits  = (const float*)d_in[0];   // [B, N, C]
    const float* regress = (const float*)d_in[1];   // [B, N, C*4]
    const float* props   = (const float*)d_in[2];   // [B, N, 4]
    float* out = (float*)d_out;                     // boxes(800) | scores(200) | labels(200)

    // Workspace layout (no overlap):
    //   [0      , 8     )  cnt     : 2 ints   (zeroed by kernel A)
    //   [8      , 16    )  done    : 2 ints   (zeroed by kernel A)
    //   [256    , 655616)  probs_t : BN*(NC-1)*NP floats (640 KB, rows 16B-aligned)
    //   [655616 , 786688)  g_key   : BN*MAXC u64 (128 KB)
    char* ws = (char*)d_ws;
    int*   cnt     = (int*)  (ws);
    int*   done    = (int*)  (ws + 8);
    float* probs_t = (float*)(ws + 256);
    ull*   g_key   = (ull*)  (ws + 256 + (size_t)BN * (NC - 1) * NP * 4);

    hipLaunchKernelGGL(softmax_probs_kernel, dim3(BN * NP / 256), dim3(256), 0, stream,
                       logits, probs_t, cnt, done);
    hipLaunchKernelGGL(nms_topk_kernel, dim3(BN * (NC - 1)), dim3(256), 0, stream,
                       probs_t, regress, props, cnt, done, g_key, out);
}